// Round 12
// baseline (305.846 us; speedup 1.0000x reference)
//
#include <hip/hip_runtime.h>
#include <hip/hip_bf16.h>
#include <math.h>

// Problem constants
#define BATCH 4
#define CIN 64
#define HH 128
#define WW 128
#define HWP (HH*WW)   // 16384

// ws layout (float indices):
//  OFF  : [4][B][18][HW] fp32     at OFF_OFF   (4,718,592 floats)
//  CAT  : [B][256][HW]  fp16      at CAT_OFF   (16,777,216 halves = 8,388,608 floats)
//  XHWC : [B][HW][64]   fp16      at XHWC_OFF  (4,194,304 halves = 2,097,152 floats)
//  WTH  : [4][64][9][64] fp16     at WTH_OFF   (deform weights, A-rows by o)
//  OWH  : [4][9][32][64] fp16     at OWH_OFF   (offset weights, o-padded 18->32)
//  G, SCALE : [B][256] fp32
#define OFF_OFF   0
#define CAT_OFF   4718592
#define XHWC_OFF  (CAT_OFF + 8388608)
#define WTH_OFF   (XHWC_OFF + 2097152)
#define OWH_OFF   (WTH_OFF + 73728)
#define G_OFF     (OWH_OFF + 36864)
#define SCALE_OFF (G_OFF + 1024)

typedef _Float16 h16x2 __attribute__((ext_vector_type(2)));
typedef _Float16 h16x8 __attribute__((ext_vector_type(8)));
typedef float    f32x4 __attribute__((ext_vector_type(4)));

union h8view { h16x8 v8; h16x2 v2[4]; };

__device__ __forceinline__ int rate_of(int i) {
    return (i == 0) ? 2 : (i == 1) ? 3 : (i == 2) ? 5 : 9;
}

// ---------------------------------------------------------------------------
// Kernel 1: prep — WTH fp16 (deform A-rows), OWH fp16 (offset B-rows, padded).
// (round-10 passing version, verbatim)
// ---------------------------------------------------------------------------
__global__ __launch_bounds__(256) void prep_kernel(
    const float* __restrict__ dw, const float* __restrict__ ow,
    _Float16* __restrict__ wth, _Float16* __restrict__ owh)
{
    int idx = blockIdx.x * 256 + threadIdx.x;
    if (idx < 147456) {
        int c = idx & 63;
        int k = (idx >> 6) % 9;
        int r = idx / 576;
        int o = r & 63;
        int i = r >> 6;
        wth[idx] = (_Float16)dw[((i * 64 + o) * 64 + c) * 9 + k];
        return;
    }
    int idx2 = idx - 147456;
    if (idx2 < 73728) {
        int c = idx2 & 63;
        int r = idx2 >> 6;
        int o = r & 31;
        int r2 = r >> 5;
        int tap = r2 % 9;
        int j = r2 / 9;
        owh[idx2] = (o < 18) ? (_Float16)ow[((j * 18 + o) * 64 + c) * 9 + tap]
                             : (_Float16)0.f;
    }
}

// ---------------------------------------------------------------------------
// Kernel 1b: XHWC[b][p][c] = fp16(x[b][c][p]) — channel-last copy.
// (round-10 passing version, verbatim)
// ---------------------------------------------------------------------------
__global__ __launch_bounds__(256) void xhwc_kernel(
    const float* __restrict__ x, _Float16* __restrict__ xhwc)
{
    const int t  = threadIdx.x;
    const int b  = blockIdx.y;
    const int p0 = blockIdx.x * 64;
    const int px = t & 63;
    const int cO = t >> 6;

    const float* xb = x + (size_t)b * CIN * HWP + p0 + px;
    _Float16* xh = xhwc + ((size_t)b * HWP + p0 + px) * 64;

#pragma unroll
    for (int g = 0; g < 2; ++g) {
        const int cb = cO * 8 + g * 32;
        h16x8 v;
#pragma unroll
        for (int cj = 0; cj < 8; ++cj)
            v[cj] = (_Float16)xb[(size_t)(cb + cj) * HWP];
        *(h16x8*)(xh + cb) = v;
    }
}

// ---------------------------------------------------------------------------
// Kernel 2: offset conv — ROW-GROUP staging: the 3 taps of kernel row g
// differ only by x-shift (ix-1)*d, so stage ONE (64+2d)-px band per group
// and run 3 taps' MFMAs from shifted LDS views (A row = px + ix*d <= 81).
// Staging insts / LDS traffic ~2.3x lower, barriers 18 -> 6, 12 MFMAs per
// stage.  Group g+1 loads hoisted over group g's MFMAs (single buffer,
// 2 barriers per group).  grid (256, 16) z = j*4+b.
// Layouts (HW-verified): A[m=lane&15][k=quad*8+j], B[k=quad*8+j][n=lane&15],
// D[m=quad*4+r][n=lane&15].
// ---------------------------------------------------------------------------
__global__ __launch_bounds__(256) void offset_mfma_kernel(
    const _Float16* __restrict__ xhwc, const _Float16* __restrict__ owh,
    const float* __restrict__ ob, float* __restrict__ off)
{
    __shared__ __align__(16) _Float16 S2[82][72];   // 11,808 B

    const int t  = threadIdx.x;
    const int z  = blockIdx.y;
    const int j  = z >> 2, b = z & 3;
    const int d  = rate_of(j);
    const int p0 = blockIdx.x * 64;
    const int ph = p0 >> 7;            // all tile px share this row
    const int cb0 = p0 & 127;          // col base (0 or 64)

    const int wv = t >> 6, lane = t & 63;
    const int nl = lane & 15, quad = lane >> 4;

    const _Float16* xh = xhwc + (size_t)b * HWP * 64;

    const int width = 64 + 2 * d;      // staged band width (<= 82)
    const int ntask = width * 8;       // (sp, chunk) tasks (<= 656)

    f32x4 acc[2];
    acc[0] = (f32x4){0.f, 0.f, 0.f, 0.f};
    acc[1] = (f32x4){0.f, 0.f, 0.f, 0.f};

    h16x8 sv[3];

    auto stage_load = [&](int g) {
        const int ys = ph + (g - 1) * d;
        const bool rowok = (unsigned)ys < (unsigned)HH;
#pragma unroll
        for (int q = 0; q < 3; ++q) {
            const int task = q * 256 + t;
            h16x8 vv = {};
            if (task < ntask) {
                const int sp = task >> 3, ch = task & 7;
                const int xs = cb0 - d + sp;
                if (rowok && (unsigned)xs < (unsigned)WW)
                    vv = *(const h16x8*)(xh + ((size_t)(ys * WW + xs)) * 64 + ch * 8);
            }
            sv[q] = vv;
        }
    };
    auto stage_store = [&]() {
#pragma unroll
        for (int q = 0; q < 3; ++q) {
            const int task = q * 256 + t;
            if (task < ntask) {
                const int sp = task >> 3, ch = task & 7;
                *(h16x8*)&S2[sp][ch * 8] = sv[q];
            }
        }
    };

    // prologue: group 0 (taps 0..2)
    stage_load(0);
    stage_store();
    __syncthreads();

    for (int g = 0; g < 3; ++g) {
        if (g < 2) stage_load(g + 1);      // VMEM in flight during MFMAs

        // ---- 3 taps from shifted views of the staged band ----
#pragma unroll
        for (int ix = 0; ix < 3; ++ix) {
            const int k = g * 3 + ix;
#pragma unroll
            for (int q2 = 0; q2 < 2; ++q2) {
                h16x8 a = *(const h16x8*)&S2[wv * 16 + nl + ix * d][q2 * 32 + quad * 8];
#pragma unroll
                for (int nt = 0; nt < 2; ++nt) {
                    const _Float16* brow = owh
                        + ((size_t)((j * 9 + k) * 32 + nt * 16 + nl)) * 64;
                    h16x8 bf = *(const h16x8*)&brow[q2 * 32 + quad * 8];
                    acc[nt] = __builtin_amdgcn_mfma_f32_16x16x32_f16(a, bf, acc[nt], 0, 0, 0);
                }
            }
        }

        __syncthreads();                   // MFMA reads of S2 complete
        if (g < 2) stage_store();
        __syncthreads();                   // stores visible
    }

    // ---- store: px = wv*16+quad*4+r, o = nt*16+nl (only o<18) ----
    float* op = off + (size_t)z * 18 * HWP + p0;
#pragma unroll
    for (int nt = 0; nt < 2; ++nt) {
        const int o = nt * 16 + nl;
        if (o < 18) {
            const float bias = ob[j * 18 + o];
#pragma unroll
            for (int r = 0; r < 4; ++r) {
                const int pxl = wv * 16 + quad * 4 + r;
                op[(size_t)o * HWP + pxl] = fmaxf(acc[nt][r] + bias, 0.f);
            }
        }
    }
}

// ---------------------------------------------------------------------------
// Kernel 3: deformable conv — round-11 dataflow with SINGLE-buffer S
// (18.4 KB -> occupancy back to round-10 level) and hoisted gather loads:
// gather(k+1) issued before MFMA(k); blend+store after a barrier.
// Loop: gather(k+1) -> MFMA(k) -> barrier -> blend+store -> barrier.
// Race-free: MFMA(k) reads S; the store that overwrites S happens after
// barrier A; MFMA(k+1) happens after barrier B.
// grid (128, 16) z=i*4+b, block 256.
// ---------------------------------------------------------------------------
__global__ __launch_bounds__(256) void deform_mfma_kernel(
    const _Float16* __restrict__ xhwc, const _Float16* __restrict__ wth,
    const float* __restrict__ off, _Float16* __restrict__ cat)
{
    __shared__ __align__(16) _Float16 S[128][72];   // 18,432 B

    const int t  = threadIdx.x;
    const int z  = blockIdx.y;
    const int i  = z >> 2, b = z & 3;
    const int d  = rate_of(i);
    const int j  = (i + 3) & 3;
    const int ty = blockIdx.x >> 1;    // row-pair 0..63
    const int tx = blockIdx.x & 1;     // col-half 0..1

    const int chunk = t & 7;           // c-octet 0..7
    const int pxb   = t >> 3;          // pixel 0..31 (+32/iter)
    const int cb    = chunk * 8;

    const int wv = t >> 6, lane = t & 63;
    const int nl = lane & 15, quad = lane >> 4;

    const _Float16* xh = xhwc + (size_t)b * HWP * 64;
    const float* offb = off + ((size_t)(j * 4 + b) * 18) * HWP;

    // this thread's 4 pixels (it*32 + pxb)
    int phv[4], pwv[4], pgv[4];
#pragma unroll
    for (int it = 0; it < 4; ++it) {
        const int psub = it * 32 + pxb;
        phv[it] = ty * 2 + (psub >> 6);
        pwv[it] = tx * 64 + (psub & 63);
        pgv[it] = phv[it] * WW + pwv[it];
    }

    f32x4 acc[8];                      // [mt][nt]
#pragma unroll
    for (int a = 0; a < 8; ++a) acc[a] = (f32x4){0.f, 0.f, 0.f, 0.f};

    h8view u[4][4];                    // in-flight gather data [it][corner]
    h16x2  wp[4][4];                   // packed bilinear weights [it][corner]
    float  ocy[4], ocx[4];             // dy,dx for the tap being gathered
    float  ony[4], onx[4];             // dy,dx prefetch one tap ahead

    // geometry + gather-issue for tap kk using ocy/ocx
    auto gather = [&](int kk) {
        const int iy = kk / 3, ix = kk % 3;
#pragma unroll
        for (int it = 0; it < 4; ++it) {
            float py = (float)(phv[it] + (iy - 1) * d) + ocy[it];
            float px = (float)(pwv[it] + (ix - 1) * d) + ocx[it];
            float fy0 = floorf(py), fx0 = floorf(px);
            float wy1 = py - fy0, wx1 = px - fx0;
            float wy0 = 1.f - wy1, wx0 = 1.f - wx1;
            int y0 = (int)fy0, x0 = (int)fx0;
            int y1 = y0 + 1,  x1 = x0 + 1;
            bool vy0 = (unsigned)y0 < (unsigned)HH, vy1 = (unsigned)y1 < (unsigned)HH;
            bool vx0 = (unsigned)x0 < (unsigned)WW, vx1 = (unsigned)x1 < (unsigned)WW;
            int yc0 = min(max(y0, 0), HH - 1), yc1 = min(max(y1, 0), HH - 1);
            int xc0 = min(max(x0, 0), WW - 1), xc1 = min(max(x1, 0), WW - 1);
            float w00 = (vy0 && vx0) ? wy0 * wx0 : 0.f;
            float w01 = (vy0 && vx1) ? wy0 * wx1 : 0.f;
            float w10 = (vy1 && vx0) ? wy1 * wx0 : 0.f;
            float w11 = (vy1 && vx1) ? wy1 * wx1 : 0.f;
            const _Float16 h00 = (_Float16)w00, h01 = (_Float16)w01;
            const _Float16 h10 = (_Float16)w10, h11 = (_Float16)w11;
            wp[it][0] = (h16x2){h00, h00};
            wp[it][1] = (h16x2){h01, h01};
            wp[it][2] = (h16x2){h10, h10};
            wp[it][3] = (h16x2){h11, h11};
            u[it][0].v8 = *(const h16x8*)(xh + (size_t)(yc0 * WW + xc0) * 64 + cb);
            u[it][1].v8 = *(const h16x8*)(xh + (size_t)(yc0 * WW + xc1) * 64 + cb);
            u[it][2].v8 = *(const h16x8*)(xh + (size_t)(yc1 * WW + xc0) * 64 + cb);
            u[it][3].v8 = *(const h16x8*)(xh + (size_t)(yc1 * WW + xc1) * 64 + cb);
        }
    };

    // blend in packed half2 and store to S
    auto blendstore = [&]() {
#pragma unroll
        for (int it = 0; it < 4; ++it) {
            h8view outv;
#pragma unroll
            for (int pp = 0; pp < 4; ++pp)
                outv.v2[pp] = u[it][0].v2[pp] * wp[it][0] + u[it][1].v2[pp] * wp[it][1]
                            + u[it][2].v2[pp] * wp[it][2] + u[it][3].v2[pp] * wp[it][3];
            *(h16x8*)&S[it * 32 + pxb][cb] = outv.v8;
        }
    };

    // ---- prologue: tap 0 staged, tap-1 offsets loaded ----
#pragma unroll
    for (int it = 0; it < 4; ++it) {
        ocy[it] = offb[0 * HWP + pgv[it]];
        ocx[it] = offb[1 * HWP + pgv[it]];
    }
    gather(0);
    blendstore();
#pragma unroll
    for (int it = 0; it < 4; ++it) {       // offsets for tap 1
        ocy[it] = offb[2 * HWP + pgv[it]];
        ocx[it] = offb[3 * HWP + pgv[it]];
    }
    __syncthreads();

    for (int k = 0; k < 9; ++k) {
        if (k < 8) {
            gather(k + 1);                 // gathers in flight during MFMA
            if (k < 7) {
#pragma unroll
                for (int it = 0; it < 4; ++it) {
                    ony[it] = offb[(2 * (k + 2)) * HWP + pgv[it]];
                    onx[it] = offb[(2 * (k + 2) + 1) * HWP + pgv[it]];
                }
            }
        }

        // ---- MFMA: wave wv -> pixels [wv*32,+32), all 64 o, tap k ----
#pragma unroll
        for (int q2 = 0; q2 < 2; ++q2) {
            h16x8 b0 = *(const h16x8*)&S[wv * 32 + nl][q2 * 32 + quad * 8];
            h16x8 b1 = *(const h16x8*)&S[wv * 32 + 16 + nl][q2 * 32 + quad * 8];
#pragma unroll
            for (int mt = 0; mt < 4; ++mt) {
                const _Float16* wrow = wth
                    + ((size_t)((i * 64 + mt * 16 + nl) * 9 + k)) * 64;
                h16x8 a = *(const h16x8*)&wrow[q2 * 32 + quad * 8];
                acc[mt * 2 + 0] = __builtin_amdgcn_mfma_f32_16x16x32_f16(a, b0, acc[mt * 2 + 0], 0, 0, 0);
                acc[mt * 2 + 1] = __builtin_amdgcn_mfma_f32_16x16x32_f16(a, b1, acc[mt * 2 + 1], 0, 0, 0);
            }
        }

        __syncthreads();                   // MFMA reads of S complete
        if (k < 8) {
            blendstore();                  // overwrite S with tap k+1
#pragma unroll
            for (int it = 0; it < 4; ++it) { ocy[it] = ony[it]; ocx[it] = onx[it]; }
        }
        __syncthreads();                   // stores visible
    }

    // ---- store: o = mt*16+quad*4+r, pixel = wv*32+nt*16+nl ----
#pragma unroll
    for (int mt = 0; mt < 4; ++mt) {
#pragma unroll
        for (int nt = 0; nt < 2; ++nt) {
            const int psub = wv * 32 + nt * 16 + nl;
            const int prow = ty * 2 + (psub >> 6);
            const int pcol = tx * 64 + (psub & 63);
            _Float16* cp = cat
                + ((size_t)(b * 256 + i * 64 + mt * 16 + quad * 4)) * HWP
                + prow * WW + pcol;
            const f32x4 v = acc[mt * 2 + nt];
#pragma unroll
            for (int r = 0; r < 4; ++r)
                cp[(size_t)r * HWP] = (_Float16)v[r];
        }
    }
}

// ---------------------------------------------------------------------------
// Kernel 4: per-(b,channel) spatial mean of fp16 CAT.  1024 blocks x 256.
// ---------------------------------------------------------------------------
__global__ __launch_bounds__(256) void reduce_kernel(
    const _Float16* __restrict__ cat, float* __restrict__ g)
{
    const int bc = blockIdx.x;
    const _Float16* p = cat + (size_t)bc * HWP;
    float s = 0.f;
#pragma unroll
    for (int q = 0; q < 8; ++q) {
        h16x8 v8 = *(const h16x8*)(p + q * 2048 + threadIdx.x * 8);
#pragma unroll
        for (int e = 0; e < 8; ++e) s += (float)v8[e];
    }
#pragma unroll
    for (int o = 32; o > 0; o >>= 1) s += __shfl_down(s, o, 64);
    __shared__ float ls[4];
    if ((threadIdx.x & 63) == 0) ls[threadIdx.x >> 6] = s;
    __syncthreads();
    if (threadIdx.x == 0) {
        g[bc] = (ls[0] + ls[1] + ls[2] + ls[3]) * (1.f / (float)HWP);
    }
}

// ---------------------------------------------------------------------------
// Kernel 5: SE MLP.
// ---------------------------------------------------------------------------
__global__ __launch_bounds__(256) void se_kernel(
    const float* __restrict__ g,  const float* __restrict__ w1,
    const float* __restrict__ b1, const float* __restrict__ w2,
    const float* __restrict__ b2, float* __restrict__ scale)
{
    __shared__ float gs[1024];
    __shared__ float h1s[256];
    const int t = threadIdx.x;
#pragma unroll
    for (int q = 0; q < 4; ++q) gs[q * 256 + t] = g[q * 256 + t];
    __syncthreads();
    {
        int b = t >> 6, o = t & 63;
        float a = b1[o];
        for (int c = 0; c < 256; ++c)
            a = fmaf(gs[b * 256 + c], w1[o * 256 + c], a);
        h1s[t] = fmaxf(a, 0.f);
    }
    __syncthreads();
#pragma unroll
    for (int q = 0; q < 4; ++q) {
        int idx = q * 256 + t;
        int b = idx >> 8, cc = idx & 255;
        float a = b2[cc];
#pragma unroll 8
        for (int o = 0; o < 64; ++o)
            a = fmaf(h1s[b * 64 + o], w2[cc * 64 + o], a);
        scale[idx] = 1.f + 1.f / (1.f + expf(-a));
    }
}

// ---------------------------------------------------------------------------
// Kernel 6: gated sum epilogue (fp16 CAT).
// ---------------------------------------------------------------------------
__global__ __launch_bounds__(256) void final_kernel(
    const float* __restrict__ x, const _Float16* __restrict__ cat,
    const float* __restrict__ scale, float* __restrict__ out)
{
    const int gid = blockIdx.x;
    const int p = (gid & 63) * 256 + threadIdx.x;
    const int c = (gid >> 6) & 63;
    const int b = gid >> 12;
    const float s0 = scale[b * 256 + c];
    const float s1 = scale[b * 256 + 64 + c];
    const float s2 = scale[b * 256 + 128 + c];
    const float s3 = scale[b * 256 + 192 + c];
    const _Float16* cb = cat + ((size_t)(b * 256 + c)) * HWP + p;
    float v = x[(size_t)(b * 64 + c) * HWP + p];
    v = fmaf(s0, (float)cb[0 * 64 * HWP], v);
    v = fmaf(s1, (float)cb[1 * 64 * HWP], v);
    v = fmaf(s2, (float)cb[2 * 64 * HWP], v);
    v = fmaf(s3, (float)cb[3 * 64 * HWP], v);
    out[(size_t)(b * 64 + c) * HWP + p] = v;
}

extern "C" void kernel_launch(void* const* d_in, const int* in_sizes, int n_in,
                              void* d_out, int out_size, void* d_ws, size_t ws_size,
                              hipStream_t stream) {
    const float* x  = (const float*)d_in[0];
    const float* dw = (const float*)d_in[1];
    const float* ow = (const float*)d_in[2];
    const float* ob = (const float*)d_in[3];
    const float* w1 = (const float*)d_in[4];
    const float* b1 = (const float*)d_in[5];
    const float* w2 = (const float*)d_in[6];
    const float* b2 = (const float*)d_in[7];
    float* out = (float*)d_out;
    float* ws  = (float*)d_ws;

    float* OFF      = ws + OFF_OFF;
    _Float16* CAT   = (_Float16*)(ws + CAT_OFF);
    _Float16* XHWC  = (_Float16*)(ws + XHWC_OFF);
    _Float16* WTH   = (_Float16*)(ws + WTH_OFF);
    _Float16* OWH   = (_Float16*)(ws + OWH_OFF);
    float* G        = ws + G_OFF;
    float* SCALE    = ws + SCALE_OFF;

    prep_kernel<<<864, 256, 0, stream>>>(dw, ow, WTH, OWH);
    xhwc_kernel<<<dim3(256, 4), 256, 0, stream>>>(x, XHWC);
    offset_mfma_kernel<<<dim3(256, 16), 256, 0, stream>>>(XHWC, OWH, ob, OFF);
    deform_mfma_kernel<<<dim3(128, 16), 256, 0, stream>>>(XHWC, WTH, OFF, CAT);
    reduce_kernel<<<1024, 256, 0, stream>>>(CAT, G);
    se_kernel<<<1, 256, 0, stream>>>(G, w1, b1, w2, b2, SCALE);
    final_kernel<<<16384, 256, 0, stream>>>(x, CAT, SCALE, out);
}